// Round 1
// baseline (1379.228 us; speedup 1.0000x reference)
//
#include <hip/hip_runtime.h>
#include <hip/hip_bf16.h>

// PhysicsAttention fused fp32 baseline.
// B=4, N=16384, DIM=256, H=8, D=64, G=64, INNER=512.
// K1: per (b,h,128-node tile): [fx|xm] = x@[W_fx_h|W_x_h]+bias (LDS-tiled GEMM),
//     logits = xm@W_slice (+b_slice)/temp, row softmax -> w; store w; pool
//     P = w^T@fx and norm = sum_n w via LDS GEMM + atomicAdd.
// K2: per (b,h): normalize tokens, q/k/v proj, 64x64 attention, out_slice.
// K3: per (b,128-node tile): loop h { A_h = w_h@outS_h (LDS); acc += A_h@W_out_h }
//     + b_out -> out.

#define B_ 4
#define N_ 16384
#define DIM_ 256
#define H_ 8
#define D_ 64
#define G_ 64
#define INNER_ 512
#define SCALE_ 0.125f

__device__ __forceinline__ void fma4x8(float (&acc)[4][8], const float4& a,
                                       const float4& b0, const float4& b1) {
  const float av[4] = {a.x, a.y, a.z, a.w};
  const float bv[8] = {b0.x, b0.y, b0.z, b0.w, b1.x, b1.y, b1.z, b1.w};
#pragma unroll
  for (int i = 0; i < 4; ++i)
#pragma unroll
    for (int j = 0; j < 8; ++j) acc[i][j] += av[i] * bv[j];
}

// ---------------------------------------------------------------- K1
__global__ __launch_bounds__(512) void k1_proj(
    const float* __restrict__ x, const float* __restrict__ Wfx,
    const float* __restrict__ bfx, const float* __restrict__ Wx,
    const float* __restrict__ bx, const float* __restrict__ Wsl,
    const float* __restrict__ bsl, const float* __restrict__ temperature,
    float* __restrict__ w_buf, float* __restrict__ tok, float* __restrict__ nrm) {
  __shared__ float lds1[8704];  // phase A: xT[32][132]; phase B/C: fx[128][68]
  __shared__ float lds2[4096];  // phase A: Wc[32][128]; phase B: Ws[64][64]
  __shared__ float lds3[8704];  // phase B: xmT[64][132]; phase C: w[128][68]

  const int t = threadIdx.x;
  const int bid = blockIdx.x;
  const int tile = bid & 127;
  const int h = (bid >> 7) & 7;
  const int b = bid >> 10;
  const int n0 = tile * 128;

  const int tx = t & 15;   // col group: c0 = tx*8 over 128 cols (fx|xm)
  const int ty = t >> 4;   // row group: r0 = ty*4 over 128 rows
  const int c0 = tx * 8;
  const int r0 = ty * 4;

  float acc[4][8];
#pragma unroll
  for (int j = 0; j < 8; ++j) {
    const int c = c0 + j;
    const float bias = (c < 64) ? bfx[h * 64 + c] : bx[h * 64 + (c - 64)];
#pragma unroll
    for (int i = 0; i < 4; ++i) acc[i][j] = bias;
  }

  const float* xb = x + (size_t)(b * N_ + n0) * DIM_;

  for (int kc = 0; kc < 8; ++kc) {
    const int k0 = kc * 32;
    // stage x^T chunk: xT[k][n], k in [0,32), n in [0,128)
#pragma unroll
    for (int i = 0; i < 2; ++i) {
      const int idx = t + 512 * i;
      const int row = idx >> 3, f4 = idx & 7;
      const float4 v = *(const float4*)(xb + (size_t)row * DIM_ + k0 + f4 * 4);
      const int kk = f4 * 4;
      lds1[(kk + 0) * 132 + row] = v.x;
      lds1[(kk + 1) * 132 + row] = v.y;
      lds1[(kk + 2) * 132 + row] = v.z;
      lds1[(kk + 3) * 132 + row] = v.w;
    }
    // stage W chunk: Wc[k][c] = (c<64 ? Wfx : Wx) head slice
#pragma unroll
    for (int i = 0; i < 2; ++i) {
      const int idx = t + 512 * i;
      const int kr = idx >> 5, f4 = idx & 31;
      const int c = f4 * 4;
      const float* src = (c < 64)
                             ? (Wfx + (size_t)(k0 + kr) * INNER_ + h * 64 + c)
                             : (Wx + (size_t)(k0 + kr) * INNER_ + h * 64 + (c - 64));
      *(float4*)&lds2[kr * 128 + c] = *(const float4*)src;
    }
    __syncthreads();
#pragma unroll
    for (int k = 0; k < 32; ++k) {
      const float4 a = *(float4*)&lds1[k * 132 + r0];
      const float4 b0 = *(float4*)&lds2[k * 128 + c0];
      const float4 b1 = *(float4*)&lds2[k * 128 + c0 + 4];
      fma4x8(acc, a, b0, b1);
    }
    __syncthreads();
  }

  // spill fx -> lds1 [128][68]; xm^T -> lds3 [64][132]; stage Ws -> lds2
  if (tx < 8) {
#pragma unroll
    for (int i = 0; i < 4; ++i)
#pragma unroll
      for (int j = 0; j < 8; ++j) lds1[(r0 + i) * 68 + c0 + j] = acc[i][j];
  } else {
#pragma unroll
    for (int i = 0; i < 4; ++i)
#pragma unroll
      for (int j = 0; j < 8; ++j) lds3[(c0 - 64 + j) * 132 + r0 + i] = acc[i][j];
  }
#pragma unroll
  for (int i = 0; i < 2; ++i) {
    const int idx = (t + 512 * i) * 4;
    *(float4*)&lds2[idx] = *(const float4*)(Wsl + idx);
  }
  __syncthreads();

  // logits GEMM: l[n][g] = sum_c xmT[c][n]*Ws[c][g] (+b_slice), then /temp
  const int lx = t & 15, ly = t >> 4;
  const int g0 = lx * 4, rb = ly * 4;
  float tmp = temperature[h];
  tmp = fminf(fmaxf(tmp, 0.1f), 5.0f);
  const float itemp = 1.0f / tmp;

  float la[4][4];
#pragma unroll
  for (int j = 0; j < 4; ++j) {
    const float bs = bsl[g0 + j];
#pragma unroll
    for (int i = 0; i < 4; ++i) la[i][j] = bs;
  }
#pragma unroll 4
  for (int k = 0; k < 64; ++k) {
    const float4 a = *(float4*)&lds3[k * 132 + rb];
    const float4 bb = *(float4*)&lds2[k * 64 + g0];
    const float av[4] = {a.x, a.y, a.z, a.w};
    const float bv[4] = {bb.x, bb.y, bb.z, bb.w};
#pragma unroll
    for (int i = 0; i < 4; ++i)
#pragma unroll
      for (int j = 0; j < 4; ++j) la[i][j] += av[i] * bv[j];
  }
#pragma unroll
  for (int i = 0; i < 4; ++i)
#pragma unroll
    for (int j = 0; j < 4; ++j) la[i][j] *= itemp;

  // row softmax over 64 (16 lanes x 4 each) via shfl_xor within 16-lane groups
  float wv[4][4];
#pragma unroll
  for (int i = 0; i < 4; ++i) {
    float m = fmaxf(fmaxf(la[i][0], la[i][1]), fmaxf(la[i][2], la[i][3]));
    m = fmaxf(m, __shfl_xor(m, 1));
    m = fmaxf(m, __shfl_xor(m, 2));
    m = fmaxf(m, __shfl_xor(m, 4));
    m = fmaxf(m, __shfl_xor(m, 8));
    float s = 0.f;
#pragma unroll
    for (int j = 0; j < 4; ++j) {
      wv[i][j] = __expf(la[i][j] - m);
      s += wv[i][j];
    }
    s += __shfl_xor(s, 1);
    s += __shfl_xor(s, 2);
    s += __shfl_xor(s, 4);
    s += __shfl_xor(s, 8);
    const float inv = 1.0f / s;
#pragma unroll
    for (int j = 0; j < 4; ++j) wv[i][j] *= inv;
  }

  __syncthreads();  // all xmT reads done before overwriting lds3 with w

  float* wgl = w_buf + ((size_t)(b * H_ + h) * N_ + n0) * G_;
#pragma unroll
  for (int i = 0; i < 4; ++i) {
    float4 v;
    v.x = wv[i][0]; v.y = wv[i][1]; v.z = wv[i][2]; v.w = wv[i][3];
    *(float4*)&lds3[(rb + i) * 68 + g0] = v;
    *(float4*)(wgl + (size_t)(rb + i) * G_ + g0) = v;
  }
  __syncthreads();

  // pooling: P[g][c] = sum_n w[n][g]*fx[n][c]; norm[g] = sum_n w[n][g]
  const int px = t & 15, py = t >> 4;
  const int cp = px * 4, gp = py * 2;
  float pa[2][4] = {{0.f, 0.f, 0.f, 0.f}, {0.f, 0.f, 0.f, 0.f}};
  float na0 = 0.f, na1 = 0.f;
#pragma unroll 4
  for (int n = 0; n < 128; ++n) {
    const float w0 = lds3[n * 68 + gp];
    const float w1 = lds3[n * 68 + gp + 1];
    const float4 f = *(float4*)&lds1[n * 68 + cp];
    pa[0][0] += w0 * f.x; pa[0][1] += w0 * f.y; pa[0][2] += w0 * f.z; pa[0][3] += w0 * f.w;
    pa[1][0] += w1 * f.x; pa[1][1] += w1 * f.y; pa[1][2] += w1 * f.z; pa[1][3] += w1 * f.w;
    na0 += w0; na1 += w1;
  }
  float* tk = tok + (size_t)(b * H_ + h) * G_ * D_;
#pragma unroll
  for (int gi = 0; gi < 2; ++gi)
#pragma unroll
    for (int j = 0; j < 4; ++j) atomicAdd(tk + (gp + gi) * D_ + cp + j, pa[gi][j]);
  if (px == 0) {
    atomicAdd(nrm + (size_t)(b * H_ + h) * G_ + gp, na0);
    atomicAdd(nrm + (size_t)(b * H_ + h) * G_ + gp + 1, na1);
  }
}

// ---------------------------------------------------------------- K2
__global__ __launch_bounds__(256) void k2_attn(
    const float* __restrict__ tok, const float* __restrict__ nrm,
    const float* __restrict__ Wq, const float* __restrict__ Wk,
    const float* __restrict__ Wv, float* __restrict__ outS) {
  __shared__ float st[64 * 65];
  __shared__ float qs[64 * 65];
  __shared__ float ks[64 * 68];
  __shared__ float vs[64 * 68];
  const int t = threadIdx.x;
  const int g = t & 63, qd = t >> 6;
  const int bh = blockIdx.x;

  const float rn = 1.0f / (nrm[bh * 64 + g] + 1e-5f);
  const float* tkr = tok + (size_t)bh * 4096 + g * 64;
#pragma unroll
  for (int dd = 0; dd < 16; ++dd) {
    const int d = qd * 16 + dd;
    st[g * 65 + d] = tkr[d] * rn;
  }
  __syncthreads();

  // q/k/v projection: each thread does 16 d's of row g
  float qa[16], ka[16], va[16];
#pragma unroll
  for (int dd = 0; dd < 16; ++dd) { qa[dd] = 0.f; ka[dd] = 0.f; va[dd] = 0.f; }
  for (int c = 0; c < 64; ++c) {
    const float s = st[g * 65 + c];
    const float* wqp = Wq + c * 64 + qd * 16;
    const float* wkp = Wk + c * 64 + qd * 16;
    const float* wvp = Wv + c * 64 + qd * 16;
#pragma unroll
    for (int dd = 0; dd < 16; ++dd) {
      qa[dd] += s * wqp[dd];
      ka[dd] += s * wkp[dd];
      va[dd] += s * wvp[dd];
    }
  }
#pragma unroll
  for (int dd = 0; dd < 16; ++dd) {
    const int d = qd * 16 + dd;
    qs[g * 65 + d] = qa[dd];
    ks[g * 68 + d] = ka[dd];
    vs[g * 68 + d] = va[dd];
  }
  __syncthreads();

  // scores for j in [qd*16, qd*16+16)
  float qr[64];
#pragma unroll
  for (int c = 0; c < 64; ++c) qr[c] = qs[g * 65 + c];
  float sc[16];
#pragma unroll
  for (int jj = 0; jj < 16; ++jj) {
    const int j = qd * 16 + jj;
    float a = 0.f;
#pragma unroll
    for (int c4 = 0; c4 < 16; ++c4) {
      const float4 kv = *(float4*)&ks[j * 68 + c4 * 4];
      a += qr[c4 * 4 + 0] * kv.x + qr[c4 * 4 + 1] * kv.y +
           qr[c4 * 4 + 2] * kv.z + qr[c4 * 4 + 3] * kv.w;
    }
    sc[jj] = a * SCALE_;
  }

  // cross-quarter softmax via LDS (reuse st region)
  float* red = st;
  float m = sc[0];
#pragma unroll
  for (int jj = 1; jj < 16; ++jj) m = fmaxf(m, sc[jj]);
  red[qd * 64 + g] = m;
  __syncthreads();
  m = fmaxf(fmaxf(red[g], red[64 + g]), fmaxf(red[128 + g], red[192 + g]));
  float s = 0.f;
#pragma unroll
  for (int jj = 0; jj < 16; ++jj) {
    sc[jj] = __expf(sc[jj] - m);
    s += sc[jj];
  }
  red[256 + qd * 64 + g] = s;
  __syncthreads();
  s = red[256 + g] + red[256 + 64 + g] + red[256 + 128 + g] + red[256 + 192 + g];
  const float inv = 1.0f / s;
#pragma unroll
  for (int jj = 0; jj < 16; ++jj) qs[g * 65 + qd * 16 + jj] = sc[jj] * inv;
  __syncthreads();

  float pr[64];
#pragma unroll
  for (int c = 0; c < 64; ++c) pr[c] = qs[g * 65 + c];
  float* os = outS + (size_t)bh * 4096 + g * 64;
#pragma unroll
  for (int dd = 0; dd < 16; ++dd) {
    const int d = qd * 16 + dd;
    float o = 0.f;
#pragma unroll
    for (int j = 0; j < 64; ++j) o += pr[j] * vs[j * 68 + d];
    os[d] = o;
  }
}

// ---------------------------------------------------------------- K3
__global__ __launch_bounds__(512) void k3_out(
    const float* __restrict__ w_buf, const float* __restrict__ outS,
    const float* __restrict__ Wout, const float* __restrict__ bout,
    float* __restrict__ out) {
  __shared__ float wl[128 * 68];   // w tile [n][g]
  __shared__ float sl[64 * 64];    // outS  [g][c]
  __shared__ float alT[64 * 132];  // A^T   [c][n]
  const int t = threadIdx.x;
  const int bid = blockIdx.x;
  const int tile = bid & 127;
  const int b = bid >> 7;
  const int n0 = tile * 128;

  const int tx = t & 31, ty = t >> 5;
  const int col0 = tx * 8, r0 = ty * 8;
  const int sx = t & 15, sy = t >> 4;
  const int cd0 = sx * 4, rs0 = sy * 4;

  float acc[8][8];
#pragma unroll
  for (int j = 0; j < 8; ++j) {
    const float bo = bout[col0 + j];
#pragma unroll
    for (int i = 0; i < 8; ++i) acc[i][j] = bo;
  }

  for (int h = 0; h < 8; ++h) {
    const float* wg = w_buf + ((size_t)(b * H_ + h) * N_ + n0) * G_;
#pragma unroll
    for (int i = 0; i < 4; ++i) {
      const int idx = t + 512 * i;
      const int row = idx >> 4, f4 = idx & 15;
      *(float4*)&wl[row * 68 + f4 * 4] = *(const float4*)(wg + (size_t)row * G_ + f4 * 4);
    }
    const float* sg = outS + (size_t)(b * H_ + h) * 4096;
#pragma unroll
    for (int i = 0; i < 2; ++i) {
      const int idx = (t + 512 * i) * 4;
      *(float4*)&sl[idx] = *(const float4*)(sg + idx);
    }
    __syncthreads();

    // A[r][cd] = sum_g wl[r][g]*sl[g][cd]
    float sa[4][4];
#pragma unroll
    for (int i = 0; i < 4; ++i)
#pragma unroll
      for (int j = 0; j < 4; ++j) sa[i][j] = 0.f;
#pragma unroll 4
    for (int g = 0; g < 64; ++g) {
      const float a0 = wl[(rs0 + 0) * 68 + g];
      const float a1 = wl[(rs0 + 1) * 68 + g];
      const float a2 = wl[(rs0 + 2) * 68 + g];
      const float a3 = wl[(rs0 + 3) * 68 + g];
      const float4 bb = *(float4*)&sl[g * 64 + cd0];
      const float bv[4] = {bb.x, bb.y, bb.z, bb.w};
#pragma unroll
      for (int j = 0; j < 4; ++j) {
        sa[0][j] += a0 * bv[j];
        sa[1][j] += a1 * bv[j];
        sa[2][j] += a2 * bv[j];
        sa[3][j] += a3 * bv[j];
      }
    }
#pragma unroll
    for (int i = 0; i < 4; ++i)
#pragma unroll
      for (int j = 0; j < 4; ++j) alT[(cd0 + j) * 132 + rs0 + i] = sa[i][j];
    __syncthreads();

    // acc += A^T(k)[r] * Wout[h*64+k][col]
    const float* wo = Wout + (size_t)(h * 64) * DIM_;
#pragma unroll 2
    for (int k = 0; k < 64; ++k) {
      const float4 a0 = *(float4*)&alT[k * 132 + r0];
      const float4 a1 = *(float4*)&alT[k * 132 + r0 + 4];
      const float4 b0 = *(const float4*)(wo + (size_t)k * DIM_ + col0);
      const float4 b1 = *(const float4*)(wo + (size_t)k * DIM_ + col0 + 4);
      const float av[8] = {a0.x, a0.y, a0.z, a0.w, a1.x, a1.y, a1.z, a1.w};
      const float bv[8] = {b0.x, b0.y, b0.z, b0.w, b1.x, b1.y, b1.z, b1.w};
#pragma unroll
      for (int i = 0; i < 8; ++i)
#pragma unroll
        for (int j = 0; j < 8; ++j) acc[i][j] += av[i] * bv[j];
    }
    __syncthreads();
  }

  float* og = out + (size_t)(b * N_ + n0) * DIM_;
#pragma unroll
  for (int i = 0; i < 8; ++i) {
    float4 v0, v1;
    v0.x = acc[i][0]; v0.y = acc[i][1]; v0.z = acc[i][2]; v0.w = acc[i][3];
    v1.x = acc[i][4]; v1.y = acc[i][5]; v1.z = acc[i][6]; v1.w = acc[i][7];
    *(float4*)(og + (size_t)(r0 + i) * DIM_ + col0) = v0;
    *(float4*)(og + (size_t)(r0 + i) * DIM_ + col0 + 4) = v1;
  }
}

// ---------------------------------------------------------------- launch
extern "C" void kernel_launch(void* const* d_in, const int* in_sizes, int n_in,
                              void* d_out, int out_size, void* d_ws, size_t ws_size,
                              hipStream_t stream) {
  const float* x = (const float*)d_in[0];
  const float* Wfx = (const float*)d_in[1];
  const float* bfx = (const float*)d_in[2];
  const float* Wx = (const float*)d_in[3];
  const float* bx = (const float*)d_in[4];
  const float* Wsl = (const float*)d_in[5];
  const float* bsl = (const float*)d_in[6];
  const float* Wq = (const float*)d_in[7];
  const float* Wk = (const float*)d_in[8];
  const float* Wv = (const float*)d_in[9];
  const float* Wout = (const float*)d_in[10];
  const float* bout = (const float*)d_in[11];
  const float* temp = (const float*)d_in[12];

  char* ws = (char*)d_ws;
  float* w_buf = (float*)ws;                                        // 128 MiB
  float* tok = (float*)(ws + 134217728);                            // 512 KiB
  float* nrm = (float*)(ws + 134217728 + 524288);                   // 8 KiB
  float* outS = (float*)(ws + 134217728 + 524288 + 8192);           // 512 KiB

  hipMemsetAsync(tok, 0, 524288 + 8192, stream);

  k1_proj<<<dim3(B_ * H_ * (N_ / 128)), dim3(512), 0, stream>>>(
      x, Wfx, bfx, Wx, bx, Wsl, bsl, temp, w_buf, tok, nrm);
  k2_attn<<<dim3(B_ * H_), dim3(256), 0, stream>>>(tok, nrm, Wq, Wk, Wv, outS);
  k3_out<<<dim3(B_ * (N_ / 128)), dim3(512), 0, stream>>>(
      w_buf, outS, Wout, bout, (float*)d_out);
}

// Round 5
// 591.984 us; speedup vs baseline: 2.3298x; 2.3298x over previous
//
#include <hip/hip_runtime.h>
#include <hip/hip_bf16.h>

// PhysicsAttention MFMA bf16 version.
// B=4, N=16384, DIM=256, H=8, D=64, G=64, INNER=512.
// k0_prep: split x -> xh/xl bf16; transpose+split weights into MFMA-friendly layouts.
// k1: per (b,h,128 nodes): proj GEMM (3-term split MFMA, fx as D[n x c], xm as D[c x n]),
//     logits MFMA + wave softmax, w -> wT LDS + global bf16, pooling MFMA + atomics.
// k2: tiny 64-token attention fp32, writes out_slice transposed bf16 [c][g].
// k3: per (b,128 nodes): loop h { A=outST@w^T MFMA -> a_lds; out_acc += Wot@A } + bias.

#define B_ 4
#define N_ 16384
#define DIM_ 256
#define H_ 8
#define D_ 64
#define G_ 64
#define INNER_ 512
#define SCALE_ 0.125f

typedef __attribute__((ext_vector_type(8))) short bf16x8;
typedef __attribute__((ext_vector_type(4))) float f32x4;
typedef unsigned short ushort_t;

#define MFMA(a, b, c) __builtin_amdgcn_mfma_f32_16x16x32_bf16((a), (b), (c), 0, 0, 0)

__device__ __forceinline__ ushort_t f2bf(float f) {
  unsigned u = __builtin_bit_cast(unsigned, f);
  u += 0x7FFFu + ((u >> 16) & 1u);
  return (ushort_t)(u >> 16);
}
__device__ __forceinline__ float bf2f(ushort_t h) {
  return __builtin_bit_cast(float, ((unsigned)h) << 16);
}
__device__ __forceinline__ uint2 pack4(f32x4 v) {
  uint2 r;
  r.x = (unsigned)f2bf(v[0]) | ((unsigned)f2bf(v[1]) << 16);
  r.y = (unsigned)f2bf(v[2]) | ((unsigned)f2bf(v[3]) << 16);
  return r;
}

// ---------------------------------------------------------------- prep
__global__ __launch_bounds__(256) void k0_prep(
    const float* __restrict__ x, const float* __restrict__ Wfx,
    const float* __restrict__ Wx, const float* __restrict__ Wsl,
    const float* __restrict__ Wout, ushort_t* __restrict__ xh,
    ushort_t* __restrict__ xl, ushort_t* __restrict__ wph,
    ushort_t* __restrict__ wpl, ushort_t* __restrict__ wslt,
    ushort_t* __restrict__ wot) {
  const int bid = blockIdx.x;
  const int t = threadIdx.x;
  if (bid < 2048) {
    // x split: 16777216 floats = 4194304 float4; 524288 threads x 8
    const float4* x4 = (const float4*)x;
    const int base = bid * 256 + t;
#pragma unroll
    for (int i = 0; i < 8; ++i) {
      const int idx = base + i * 524288;
      const float4 v = x4[idx];
      ushort_t h0 = f2bf(v.x), h1 = f2bf(v.y), h2 = f2bf(v.z), h3 = f2bf(v.w);
      uint2 hp, lp;
      hp.x = (unsigned)h0 | ((unsigned)h1 << 16);
      hp.y = (unsigned)h2 | ((unsigned)h3 << 16);
      lp.x = (unsigned)f2bf(v.x - bf2f(h0)) | ((unsigned)f2bf(v.y - bf2f(h1)) << 16);
      lp.y = (unsigned)f2bf(v.z - bf2f(h2)) | ((unsigned)f2bf(v.w - bf2f(h3)) << 16);
      *(uint2*)&xh[(size_t)idx * 4] = hp;
      *(uint2*)&xl[(size_t)idx * 4] = lp;
    }
  } else if (bid < 3072) {
    // Wp [h][c=128][k=256]: c<64 -> Wfx col h*64+c ; else Wx col h*64+(c-64)
    const int idx = (bid - 2048) * 256 + t;
    const int k = idx & 255, c = (idx >> 8) & 127, h = idx >> 15;
    const float v = (c < 64) ? Wfx[(size_t)k * INNER_ + h * 64 + c]
                             : Wx[(size_t)k * INNER_ + h * 64 + (c - 64)];
    const ushort_t hi = f2bf(v);
    wph[idx] = hi;
    wpl[idx] = f2bf(v - bf2f(hi));
  } else if (bid < 3088) {
    // Wslt [g][d] = W_slice[d][g]
    const int idx = (bid - 3072) * 256 + t;
    const int d = idx & 63, g = idx >> 6;
    wslt[idx] = f2bf(Wsl[d * 64 + g]);
  } else {
    // Wot [h][d=256][c=64] = W_out[h*64+c][d]   (512 blocks)
    const int idx = (bid - 3088) * 256 + t;
    const int c = idx & 63, d = (idx >> 6) & 255, h = idx >> 14;
    wot[idx] = f2bf(Wout[(size_t)(h * 64 + c) * DIM_ + d]);
  }
}

// ---------------------------------------------------------------- K1
// LDS layout (bytes):
//   [0, 40960): staging  xsh[128*40] | xsl | wsh[128*40] | wsl  (shorts, off 0/5120/10240/15360)
//   overlay after proj: [0,18432): xmS[128][72] ; [18432,35840): wT[64][136]
//   [40960, 58368): fxT[64][136]
__global__ __launch_bounds__(512, 1) void k1_proj(
    const ushort_t* __restrict__ xh, const ushort_t* __restrict__ xl,
    const ushort_t* __restrict__ wph, const ushort_t* __restrict__ wpl,
    const ushort_t* __restrict__ wslt, const float* __restrict__ bfx,
    const float* __restrict__ bx, const float* __restrict__ bsl,
    const float* __restrict__ temperature, ushort_t* __restrict__ w_buf,
    float* __restrict__ tok, float* __restrict__ nrm) {
  __shared__ char lds[58368];
  ushort_t* stg = (ushort_t*)lds;
  ushort_t* xmS = (ushort_t*)lds;                  // [128][72] (overlay, post-proj)
  ushort_t* wT = (ushort_t*)(lds + 18432);         // [64][136]
  ushort_t* fxT = (ushort_t*)(lds + 40960);        // [64][136]

  const int t = threadIdx.x;
  const int l = t & 63, w = t >> 6;
  const int l15 = l & 15, l4 = l >> 4;
  const int bid = blockIdx.x;
  const int tile = bid & 127, h = (bid >> 7) & 7, b = bid >> 10;
  const int n0 = tile * 128;
  const int bh = b * H_ + h;
  const int nb = (w >> 1) * 32, cb = (w & 1) * 32;

  // ---- proj accumulators (+bias)
  f32x4 afx[2][2];  // fx: D[n x c], [nf][cf]
  f32x4 axm[2][2];  // xm: D[c x n], [cf][nf]
#pragma unroll
  for (int cf = 0; cf < 2; ++cf) {
    const float bfv = bfx[h * 64 + cb + cf * 16 + l15];
#pragma unroll
    for (int nf = 0; nf < 2; ++nf) {
      afx[nf][cf][0] = bfv; afx[nf][cf][1] = bfv; afx[nf][cf][2] = bfv; afx[nf][cf][3] = bfv;
#pragma unroll
      for (int r = 0; r < 4; ++r) axm[cf][nf][r] = bx[h * 64 + cb + cf * 16 + l4 * 4 + r];
    }
  }

  const ushort_t* xhg = xh + (size_t)(b * N_ + n0) * 256;
  const ushort_t* xlg = xl + (size_t)(b * N_ + n0) * 256;
  const ushort_t* wphg = wph + h * 32768;
  const ushort_t* wplg = wpl + h * 32768;

  const int srow = t >> 2, sq = t & 3;
  const int soff = srow * 40 + sq * 8;
  const int goff = srow * 256 + sq * 8;

  for (int ks = 0; ks < 8; ++ks) {
    const int k0 = ks * 32;
    *(int4*)&stg[soff] = *(const int4*)&xhg[goff + k0];
    *(int4*)&stg[5120 + soff] = *(const int4*)&xlg[goff + k0];
    *(int4*)&stg[10240 + soff] = *(const int4*)&wphg[goff + k0];
    *(int4*)&stg[15360 + soff] = *(const int4*)&wplg[goff + k0];
    __syncthreads();

    bf16x8 xfh[2], xfl[2], wfh[2], wfl[2], wmh[2], wml[2];
#pragma unroll
    for (int nf = 0; nf < 2; ++nf) {
      const int off = (nb + nf * 16 + l15) * 40 + l4 * 8;
      xfh[nf] = *(const bf16x8*)&stg[off];
      xfl[nf] = *(const bf16x8*)&stg[5120 + off];
    }
#pragma unroll
    for (int cf = 0; cf < 2; ++cf) {
      const int offc = (cb + cf * 16 + l15) * 40 + l4 * 8;
      wfh[cf] = *(const bf16x8*)&stg[10240 + offc];
      wfl[cf] = *(const bf16x8*)&stg[15360 + offc];
      const int offm = (64 + cb + cf * 16 + l15) * 40 + l4 * 8;
      wmh[cf] = *(const bf16x8*)&stg[10240 + offm];
      wml[cf] = *(const bf16x8*)&stg[15360 + offm];
    }
#pragma unroll
    for (int nf = 0; nf < 2; ++nf)
#pragma unroll
      for (int cf = 0; cf < 2; ++cf) {
        afx[nf][cf] = MFMA(xfh[nf], wfh[cf], afx[nf][cf]);
        afx[nf][cf] = MFMA(xfh[nf], wfl[cf], afx[nf][cf]);
        afx[nf][cf] = MFMA(xfl[nf], wfh[cf], afx[nf][cf]);
        axm[cf][nf] = MFMA(wmh[cf], xfh[nf], axm[cf][nf]);
        axm[cf][nf] = MFMA(wmh[cf], xfl[nf], axm[cf][nf]);
        axm[cf][nf] = MFMA(wml[cf], xfh[nf], axm[cf][nf]);
      }
    __syncthreads();
  }

  // ---- spill: fxT[c][n] and xmS[n][c] (both b64-packed)
#pragma unroll
  for (int nf = 0; nf < 2; ++nf)
#pragma unroll
    for (int cf = 0; cf < 2; ++cf) {
      const int c = cb + cf * 16 + l15;
      const int n = nb + nf * 16 + l4 * 4;
      *(uint2*)&fxT[c * 136 + n] = pack4(afx[nf][cf]);
      const int n2 = nb + nf * 16 + l15;
      const int c2 = cb + cf * 16 + l4 * 4;
      *(uint2*)&xmS[n2 * 72 + c2] = pack4(axm[cf][nf]);
    }
  __syncthreads();

  // ---- logits: D[n x g] = xmS[n][d] @ Wslt[g][d]^T ; wave owns n-range w*16
  float tmp = temperature[h];
  tmp = fminf(fmaxf(tmp, 0.1f), 5.0f);
  const float itemp = 1.0f / tmp;
  f32x4 lg[4];
#pragma unroll
  for (int gf = 0; gf < 4; ++gf) {
    const float bv = bsl[gf * 16 + l15];
    lg[gf][0] = bv; lg[gf][1] = bv; lg[gf][2] = bv; lg[gf][3] = bv;
  }
#pragma unroll
  for (int ks = 0; ks < 2; ++ks) {
    const bf16x8 aX = *(const bf16x8*)&xmS[(w * 16 + l15) * 72 + ks * 32 + l4 * 8];
#pragma unroll
    for (int gf = 0; gf < 4; ++gf) {
      const bf16x8 bW = *(const bf16x8*)&wslt[(gf * 16 + l15) * 64 + ks * 32 + l4 * 8];
      lg[gf] = MFMA(aX, bW, lg[gf]);
    }
  }

  // ---- softmax over g (rows n = w*16 + l4*4 + r; cols g = gf*16 + l15)
  float wv[4][4];  // [r][gf]
#pragma unroll
  for (int r = 0; r < 4; ++r) {
    float m = fmaxf(fmaxf(lg[0][r], lg[1][r]), fmaxf(lg[2][r], lg[3][r])) * itemp;
    m = fmaxf(m, __shfl_xor(m, 1));
    m = fmaxf(m, __shfl_xor(m, 2));
    m = fmaxf(m, __shfl_xor(m, 4));
    m = fmaxf(m, __shfl_xor(m, 8));
    float s = 0.f;
#pragma unroll
    for (int gf = 0; gf < 4; ++gf) {
      wv[r][gf] = __expf(lg[gf][r] * itemp - m);
      s += wv[r][gf];
    }
    s += __shfl_xor(s, 1);
    s += __shfl_xor(s, 2);
    s += __shfl_xor(s, 4);
    s += __shfl_xor(s, 8);
    const float inv = 1.0f / s;
#pragma unroll
    for (int gf = 0; gf < 4; ++gf) wv[r][gf] *= inv;
  }

  // norm partials: reduce over n within wave (lanes xor16/32 share g)
#pragma unroll
  for (int gf = 0; gf < 4; ++gf) {
    float pn = wv[0][gf] + wv[1][gf] + wv[2][gf] + wv[3][gf];
    pn += __shfl_xor(pn, 16);
    pn += __shfl_xor(pn, 32);
    if (l4 == 0) atomicAdd(&nrm[bh * 64 + gf * 16 + l15], pn);
  }

  // wT[g][n] writes (b64)
#pragma unroll
  for (int gf = 0; gf < 4; ++gf) {
    const int g = gf * 16 + l15;
    const int n = w * 16 + l4 * 4;
    f32x4 v;
    v[0] = wv[0][gf]; v[1] = wv[1][gf]; v[2] = wv[2][gf]; v[3] = wv[3][gf];
    *(uint2*)&wT[g * 136 + n] = pack4(v);
  }
  __syncthreads();

  // ---- w_buf global store (coalesced) via wT re-read
  {
    const int n = t >> 2, q = t & 3;
    unsigned up[8];
#pragma unroll
    for (int j = 0; j < 8; ++j) {
      const unsigned e0 = wT[(q * 16 + 2 * j) * 136 + n];
      const unsigned e1 = wT[(q * 16 + 2 * j + 1) * 136 + n];
      up[j] = e0 | (e1 << 16);
    }
    ushort_t* wg = w_buf + ((size_t)bh * N_ + n0 + n) * 64 + q * 16;
    *(int4*)&wg[0] = *(int4*)&up[0];
    *(int4*)&wg[8] = *(int4*)&up[4];
  }

  // ---- pooling: D[g x c] = wT[g][n] @ fxT[c][n]^T, K=128
  f32x4 ap[2];
  ap[0] = (f32x4)0.f; ap[1] = (f32x4)0.f;
  const int gf0 = (w * 2) >> 2, cf0 = (w * 2) & 3;
  const int gf1 = (w * 2 + 1) >> 2, cf1 = (w * 2 + 1) & 3;
#pragma unroll
  for (int ks = 0; ks < 4; ++ks) {
    const bf16x8 aW0 = *(const bf16x8*)&wT[(gf0 * 16 + l15) * 136 + ks * 32 + l4 * 8];
    const bf16x8 bF0 = *(const bf16x8*)&fxT[(cf0 * 16 + l15) * 136 + ks * 32 + l4 * 8];
    ap[0] = MFMA(aW0, bF0, ap[0]);
    const bf16x8 aW1 = *(const bf16x8*)&wT[(gf1 * 16 + l15) * 136 + ks * 32 + l4 * 8];
    const bf16x8 bF1 = *(const bf16x8*)&fxT[(cf1 * 16 + l15) * 136 + ks * 32 + l4 * 8];
    ap[1] = MFMA(aW1, bF1, ap[1]);
  }
#pragma unroll
  for (int u = 0; u < 2; ++u) {
    const int gf = (w * 2 + u) >> 2, cf = (w * 2 + u) & 3;
    const int c = cf * 16 + l15;
#pragma unroll
    for (int r = 0; r < 4; ++r) {
      const int g = gf * 16 + l4 * 4 + r;
      atomicAdd(&tok[((size_t)bh * 64 + g) * 64 + c], ap[u][r]);
    }
  }
}

// ---------------------------------------------------------------- K2
__global__ __launch_bounds__(256) void k2_attn(
    const float* __restrict__ tok, const float* __restrict__ nrm,
    const float* __restrict__ Wq, const float* __restrict__ Wk,
    const float* __restrict__ Wv, ushort_t* __restrict__ outST) {
  __shared__ float st[64 * 65];
  __shared__ float qs[64 * 65];
  __shared__ float ks[64 * 68];
  __shared__ float vs[64 * 68];
  const int t = threadIdx.x;
  const int g = t & 63, qd = t >> 6;
  const int bh = blockIdx.x;

  const float rn = 1.0f / (nrm[bh * 64 + g] + 1e-5f);
  const float* tkr = tok + (size_t)bh * 4096 + g * 64;
#pragma unroll
  for (int dd = 0; dd < 16; ++dd) {
    const int d = qd * 16 + dd;
    st[g * 65 + d] = tkr[d] * rn;
  }
  __syncthreads();

  float qa[16], ka[16], va[16];
#pragma unroll
  for (int dd = 0; dd < 16; ++dd) { qa[dd] = 0.f; ka[dd] = 0.f; va[dd] = 0.f; }
  for (int c = 0; c < 64; ++c) {
    const float s = st[g * 65 + c];
    const float* wqp = Wq + c * 64 + qd * 16;
    const float* wkp = Wk + c * 64 + qd * 16;
    const float* wvp = Wv + c * 64 + qd * 16;
#pragma unroll
    for (int dd = 0; dd < 16; ++dd) {
      qa[dd] += s * wqp[dd];
      ka[dd] += s * wkp[dd];
      va[dd] += s * wvp[dd];
    }
  }
#pragma unroll
  for (int dd = 0; dd < 16; ++dd) {
    const int d = qd * 16 + dd;
    qs[g * 65 + d] = qa[dd];
    ks[g * 68 + d] = ka[dd];
    vs[g * 68 + d] = va[dd];
  }
  __syncthreads();

  float qr[64];
#pragma unroll
  for (int c = 0; c < 64; ++c) qr[c] = qs[g * 65 + c];
  float sc[16];
#pragma unroll
  for (int jj = 0; jj < 16; ++jj) {
    const int j = qd * 16 + jj;
    float a = 0.f;
#pragma unroll
    for (int c4 = 0; c4 < 16; ++c4) {
      const float4 kv = *(float4*)&ks[j * 68 + c4 * 4];
      a += qr[c4 * 4 + 0] * kv.x + qr[c4 * 4 + 1] * kv.y +
           qr[c4 * 4 + 2] * kv.z + qr[c4 * 4 + 3] * kv.w;
    }
    sc[jj] = a * SCALE_;
  }

  float* red = st;
  float m = sc[0];
#pragma unroll
  for (int jj = 1; jj < 16; ++jj) m = fmaxf(m, sc[jj]);
  red[qd * 64 + g] = m;
  __syncthreads();
  m = fmaxf(fmaxf(red[g], red[64 + g]), fmaxf(red[128 + g], red[192 + g]));
  float s = 0.f;
#pragma unroll
  for (int jj = 0; jj < 16; ++jj) {
    sc[jj] = __expf(sc[jj] - m);
    s += sc[jj];
  }
  red[256 + qd * 64 + g] = s;
  __syncthreads();
  s = red[256 + g] + red[256 + 64 + g] + red[256 + 128 + g] + red[256 + 192 + g];
  const float inv = 1.0f / s;
#pragma unroll
  for (int jj = 0; jj < 16; ++jj) qs[g * 65 + qd * 16 + jj] = sc[jj] * inv;
  __syncthreads();

  float pr[64];
#pragma unroll
  for (int c = 0; c < 64; ++c) pr[c] = qs[g * 65 + c];
  ushort_t* os = outST + (size_t)bh * 4096;
#pragma unroll
  for (int dd = 0; dd < 16; ++dd) {
    const int d = qd * 16 + dd;
    float o = 0.f;
#pragma unroll
    for (int j = 0; j < 64; ++j) o += pr[j] * vs[j * 68 + d];
    os[d * 64 + g] = f2bf(o);  // transposed [c][g]
  }
}

// ---------------------------------------------------------------- K3
__global__ __launch_bounds__(512, 1) void k3_out(
    const ushort_t* __restrict__ w_buf, const ushort_t* __restrict__ outST,
    const ushort_t* __restrict__ wot, const float* __restrict__ bout,
    float* __restrict__ out) {
  __shared__ ushort_t a_lds[128 * 72];
  __shared__ ushort_t wot_lds[256 * 72];
  const int t = threadIdx.x;
  const int l = t & 63, w = t >> 6;
  const int l15 = l & 15, l4 = l >> 4;
  const int bid = blockIdx.x;
  const int tile = bid & 127, b = bid >> 7;
  const int n0 = tile * 128;

  f32x4 acc[16];
#pragma unroll
  for (int df = 0; df < 16; ++df)
#pragma unroll
    for (int r = 0; r < 4; ++r) acc[df][r] = bout[df * 16 + l4 * 4 + r];

  for (int h = 0; h < H_; ++h) {
    const int bh = b * H_ + h;
    __syncthreads();  // protect lds from previous-iter reads
    // stage Wot_h [256][64] -> wot_lds[256][72]
#pragma unroll
    for (int i = 0; i < 4; ++i) {
      const int idx = t + 512 * i;
      const int row = idx >> 3, q = idx & 7;
      *(int4*)&wot_lds[row * 72 + q * 8] =
          *(const int4*)&wot[((size_t)h * 256 + row) * 64 + q * 8];
    }
    // GEMM1: D[c x n] = outST[c][g] @ w[n][g]^T ; wave owns n = n0+w*16+l15
    f32x4 as_[4];
#pragma unroll
    for (int cf = 0; cf < 4; ++cf) as_[cf] = (f32x4)0.f;
#pragma unroll
    for (int ks = 0; ks < 2; ++ks) {
      const bf16x8 bW = *(const bf16x8*)&w_buf[((size_t)bh * N_ + n0 + w * 16 + l15) * 64 +
                                               ks * 32 + l4 * 8];
#pragma unroll
      for (int cf = 0; cf < 4; ++cf) {
        const bf16x8 aS = *(const bf16x8*)&outST[(size_t)bh * 4096 + (cf * 16 + l15) * 64 +
                                                 ks * 32 + l4 * 8];
        as_[cf] = MFMA(aS, bW, as_[cf]);
      }
    }
    // spill a_lds[n][c] (b64)
#pragma unroll
    for (int cf = 0; cf < 4; ++cf)
      *(uint2*)&a_lds[(w * 16 + l15) * 72 + cf * 16 + l4 * 4] = pack4(as_[cf]);
    __syncthreads();
    // GEMM2: D[d x n] += Wot[d][c] @ A[n][c]^T
#pragma unroll
    for (int ks = 0; ks < 2; ++ks) {
      const bf16x8 bA = *(const bf16x8*)&a_lds[(w * 16 + l15) * 72 + ks * 32 + l4 * 8];
#pragma unroll
      for (int df = 0; df < 16; ++df) {
        const bf16x8 aW = *(const bf16x8*)&wot_lds[(df * 16 + l15) * 72 + ks * 32 + l4 * 8];
        acc[df] = MFMA(aW, bA, acc[df]);
      }
    }
  }

  const int n = n0 + w * 16 + l15;
  float* og = out + ((size_t)b * N_ + n) * DIM_;
#pragma unroll
  for (int df = 0; df < 16; ++df) {
    float4 v;
    v.x = acc[df][0]; v.y = acc[df][1]; v.z = acc[df][2]; v.w = acc[df][3];
    *(float4*)&og[df * 16 + l4 * 4] = v;
  }
}

// ---------------------------------------------------------------- launch
extern "C" void kernel_launch(void* const* d_in, const int* in_sizes, int n_in,
                              void* d_out, int out_size, void* d_ws, size_t ws_size,
                              hipStream_t stream) {
  const float* x = (const float*)d_in[0];
  const float* Wfx = (const float*)d_in[1];
  const float* bfx = (const float*)d_in[2];
  const float* Wx = (const float*)d_in[3];
  const float* bx = (const float*)d_in[4];
  const float* Wsl = (const float*)d_in[5];
  const float* bsl = (const float*)d_in[6];
  const float* Wq = (const float*)d_in[7];
  const float* Wk = (const float*)d_in[8];
  const float* Wv = (const float*)d_in[9];
  const float* Wout = (const float*)d_in[10];
  const float* bout = (const float*)d_in[11];
  const float* temp = (const float*)d_in[12];

  char* ws = (char*)d_ws;
  ushort_t* w_buf = (ushort_t*)ws;                           // 64 MiB
  ushort_t* xh = (ushort_t*)(ws + 67108864);                 // 32 MiB
  ushort_t* xl = (ushort_t*)(ws + 100663296);                // 32 MiB
  ushort_t* wph = (ushort_t*)(ws + 134217728);               // 512 KiB
  ushort_t* wpl = (ushort_t*)(ws + 134742016);               // 512 KiB
  ushort_t* wslt = (ushort_t*)(ws + 135266304);              // 8 KiB
  ushort_t* wot = (ushort_t*)(ws + 135274496);               // 256 KiB
  ushort_t* outST = (ushort_t*)(ws + 135536640);             // 256 KiB
  float* tok = (float*)(ws + 135798784);                     // 512 KiB
  float* nrm = (float*)(ws + 136323072);                     // 8 KiB

  hipMemsetAsync(tok, 0, 524288 + 8192, stream);

  k0_prep<<<dim3(3600), dim3(256), 0, stream>>>(x, Wfx, Wx, Wsl, Wout, xh, xl,
                                                wph, wpl, wslt, wot);
  k1_proj<<<dim3(B_ * H_ * (N_ / 128)), dim3(512), 0, stream>>>(
      xh, xl, wph, wpl, wslt, bfx, bx, bsl, temp, w_buf, tok, nrm);
  k2_attn<<<dim3(B_ * H_), dim3(256), 0, stream>>>(tok, nrm, Wq, Wk, Wv, outST);
  k3_out<<<dim3(B_ * (N_ / 128)), dim3(512), 0, stream>>>(w_buf, outST, wot,
                                                          bout, (float*)d_out);
}

// Round 6
// 514.663 us; speedup vs baseline: 2.6799x; 1.1502x over previous
//
#include <hip/hip_runtime.h>
#include <hip/hip_bf16.h>

// PhysicsAttention MFMA bf16 v2 — pipelined k1 with algebraic logits fusion.
// B=4, N=16384, DIM=256, H=8, D=64, G=64, INNER=512.
// k0_prep: split x -> xh/xl bf16; W_fx head-transpose bf16; W_out transpose bf16.
// k0b: Wcomb[h] = W_x_h @ W_slice (fp32, split hi/lo bf16) + lbias = b_x@W_slice + b_slice.
// k1: per (b,h,128 nodes): double-buffered global_load_lds staging; fused
//     fx = xh@Wf (1 MFMA) and logits = x@Wcomb (3-term split) per K-step;
//     softmax -> w (LDS wT + global bf16); pooling MFMA + atomics.
// k2: tiny 64-token attention fp32 -> outST bf16 [c][g].
// k3: per (b,128 nodes): loop h { A=outST@w^T MFMA -> a_lds; acc += Wot@A } + bias.

#define B_ 4
#define N_ 16384
#define DIM_ 256
#define H_ 8
#define D_ 64
#define G_ 64
#define INNER_ 512
#define SCALE_ 0.125f

typedef __attribute__((ext_vector_type(8))) short bf16x8;
typedef __attribute__((ext_vector_type(4))) float f32x4;
typedef unsigned short ushort_t;

#define MFMA(a, b, c) __builtin_amdgcn_mfma_f32_16x16x32_bf16((a), (b), (c), 0, 0, 0)

__device__ __forceinline__ ushort_t f2bf(float f) {
  unsigned u = __builtin_bit_cast(unsigned, f);
  u += 0x7FFFu + ((u >> 16) & 1u);
  return (ushort_t)(u >> 16);
}
__device__ __forceinline__ float bf2f(ushort_t h) {
  return __builtin_bit_cast(float, ((unsigned)h) << 16);
}
__device__ __forceinline__ uint2 pack4(f32x4 v) {
  uint2 r;
  r.x = (unsigned)f2bf(v[0]) | ((unsigned)f2bf(v[1]) << 16);
  r.y = (unsigned)f2bf(v[2]) | ((unsigned)f2bf(v[3]) << 16);
  return r;
}
__device__ __forceinline__ void gload16(const ushort_t* gsrc, char* ldst) {
  // async global->LDS, 16B/lane; LDS dest = wave-uniform base + lane*16
  __builtin_amdgcn_global_load_lds(
      (const __attribute__((address_space(1))) unsigned int*)gsrc,
      (__attribute__((address_space(3))) unsigned int*)ldst, 16, 0, 0);
}

// ---------------------------------------------------------------- k0_prep
__global__ __launch_bounds__(256) void k0_prep(
    const float* __restrict__ x, const float* __restrict__ Wfx,
    const float* __restrict__ Wout, ushort_t* __restrict__ xh,
    ushort_t* __restrict__ xl, ushort_t* __restrict__ wfxt,
    ushort_t* __restrict__ wot) {
  const int bid = blockIdx.x;
  const int t = threadIdx.x;
  if (bid < 2048) {
    // x split: 16777216 floats = 4194304 float4
    const float4* x4 = (const float4*)x;
    const int base = bid * 256 + t;
#pragma unroll
    for (int i = 0; i < 8; ++i) {
      const int idx = base + i * 524288;
      const float4 v = x4[idx];
      ushort_t h0 = f2bf(v.x), h1 = f2bf(v.y), h2 = f2bf(v.z), h3 = f2bf(v.w);
      uint2 hp, lp;
      hp.x = (unsigned)h0 | ((unsigned)h1 << 16);
      hp.y = (unsigned)h2 | ((unsigned)h3 << 16);
      lp.x = (unsigned)f2bf(v.x - bf2f(h0)) | ((unsigned)f2bf(v.y - bf2f(h1)) << 16);
      lp.y = (unsigned)f2bf(v.z - bf2f(h2)) | ((unsigned)f2bf(v.w - bf2f(h3)) << 16);
      *(uint2*)&xh[(size_t)idx * 4] = hp;
      *(uint2*)&xl[(size_t)idx * 4] = lp;
    }
  } else if (bid < 2560) {
    // wfxt [h][c=64][k=256] = W_fx[k][h*64+c]  (plain bf16)
    const int f = (bid - 2048) * 256 + t;
    const int k = f & 255, c = (f >> 8) & 63, h = f >> 14;
    wfxt[f] = f2bf(Wfx[(size_t)k * INNER_ + h * 64 + c]);
  } else {
    // wot [h][d=256][c=64] = W_out[h*64+c][d]
    const int idx = (bid - 2560) * 256 + t;
    const int c = idx & 63, d = (idx >> 6) & 255, h = idx >> 14;
    wot[idx] = f2bf(Wout[(size_t)(h * 64 + c) * DIM_ + d]);
  }
}

// ---------------------------------------------------------------- k0b
// Wcomb_h = W_x_h @ W_slice  ->  wcth/wctl [h][g=64][k=256] hi/lo bf16
// lbias[h][g] = sum_dd b_x[h,dd]*W_slice[dd][g] + b_slice[g]
__global__ __launch_bounds__(256) void k0b_comb(
    const float* __restrict__ Wx, const float* __restrict__ Wsl,
    const float* __restrict__ bx, const float* __restrict__ bsl,
    ushort_t* __restrict__ wcth, ushort_t* __restrict__ wctl,
    float* __restrict__ lbias) {
  __shared__ float wsl_s[4096];    // [dd][g]
  __shared__ float wx_s[64 * 65];  // [kk][dd] padded
  const int h = blockIdx.x;
  const int t = threadIdx.x;
#pragma unroll
  for (int i = 0; i < 16; ++i) wsl_s[i * 256 + t] = Wsl[i * 256 + t];
  __syncthreads();
  if (t < 64) {
    float a = bsl[t];
    for (int dd = 0; dd < 64; ++dd) a += bx[h * 64 + dd] * wsl_s[dd * 64 + t];
    lbias[h * 64 + t] = a;
  }
  const int g = t & 63, ko = t >> 6;
  for (int kc = 0; kc < 4; ++kc) {
    __syncthreads();
#pragma unroll
    for (int i = 0; i < 16; ++i) {
      const int f = i * 256 + t;  // kk = f>>6, dd = f&63
      wx_s[(f >> 6) * 65 + (f & 63)] =
          Wx[(size_t)(kc * 64 + (f >> 6)) * INNER_ + h * 64 + (f & 63)];
    }
    __syncthreads();
    for (int kk = ko * 16; kk < ko * 16 + 16; ++kk) {
      float a = 0.f;
#pragma unroll 8
      for (int dd = 0; dd < 64; ++dd) a += wx_s[kk * 65 + dd] * wsl_s[dd * 64 + g];
      const int k = kc * 64 + kk;
      const ushort_t hi = f2bf(a);
      wcth[(size_t)(h * 64 + g) * 256 + k] = hi;
      wctl[(size_t)(h * 64 + g) * 256 + k] = f2bf(a - bf2f(hi));
    }
  }
}

// ---------------------------------------------------------------- K1
// LDS: 2 staging buffers of 28 KiB each:
//   [0,8K) xh[128][32] | [8K,16K) xl[128][32] | [16K,20K) wf[64][32]
//   [20K,24K) wch[64][32] | [24K,28K) wcl[64][32]
// post-loop overlay: fxT[64][136] @0, wT[64][136] @17408.
__global__ __launch_bounds__(512, 4) void k1_proj(
    const ushort_t* __restrict__ xh, const ushort_t* __restrict__ xl,
    const ushort_t* __restrict__ wfxt, const ushort_t* __restrict__ wcth,
    const ushort_t* __restrict__ wctl, const float* __restrict__ bfx,
    const float* __restrict__ lbias, const float* __restrict__ temperature,
    ushort_t* __restrict__ w_buf, float* __restrict__ tok,
    float* __restrict__ nrm) {
  __shared__ __align__(16) char lds[57344];
  ushort_t* fxT = (ushort_t*)lds;           // [64][136]
  ushort_t* wT = (ushort_t*)(lds + 17408);  // [64][136]

  const int t = threadIdx.x;
  const int l = t & 63, w = t >> 6;
  const int l15 = l & 15, l4 = l >> 4;
  const int bid = blockIdx.x;
  const int tile = bid & 127, h = (bid >> 7) & 7, b = bid >> 10;
  const int n0 = tile * 128;
  const int bh = b * H_ + h;

  const ushort_t* xhg = xh + (size_t)(b * N_ + n0) * 256;
  const ushort_t* xlg = xl + (size_t)(b * N_ + n0) * 256;
  const ushort_t* wfg = wfxt + h * 16384;
  const ushort_t* wchg = wcth + h * 16384;
  const ushort_t* wclg = wctl + h * 16384;

  const int srow = l >> 2;            // staging: lane -> row offset
  const int schunk = (l & 3) * 8;     // and 16B chunk within row

  f32x4 afx[4], alg[4];  // fx D[n x c] (wave rows w*16), logits D[n x g]
#pragma unroll
  for (int cf = 0; cf < 4; ++cf) {
    const float bf_ = bfx[h * 64 + cf * 16 + l15];
    afx[cf][0] = bf_; afx[cf][1] = bf_; afx[cf][2] = bf_; afx[cf][3] = bf_;
    const float lb_ = lbias[h * 64 + cf * 16 + l15];
    alg[cf][0] = lb_; alg[cf][1] = lb_; alg[cf][2] = lb_; alg[cf][3] = lb_;
  }

#define STAGE(cur, ks)                                                          \
  {                                                                             \
    const int k0_ = (ks) * 32;                                                  \
    char* sb_ = lds + (cur) * 28672;                                            \
    gload16(xhg + (size_t)(w * 16 + srow) * 256 + k0_ + schunk, sb_ + w * 1024);\
    gload16(xlg + (size_t)(w * 16 + srow) * 256 + k0_ + schunk,                 \
            sb_ + 8192 + w * 1024);                                             \
    if (w < 4) {                                                                \
      gload16(wfg + (size_t)(w * 16 + srow) * 256 + k0_ + schunk,               \
              sb_ + 16384 + w * 1024);                                          \
      gload16(wclg + (size_t)(w * 16 + srow) * 256 + k0_ + schunk,              \
              sb_ + 24576 + w * 1024);                                          \
    } else {                                                                    \
      gload16(wchg + (size_t)((w - 4) * 16 + srow) * 256 + k0_ + schunk,        \
              sb_ + 20480 + (w - 4) * 1024);                                    \
    }                                                                           \
  }

  STAGE(0, 0);
  __syncthreads();  // implicit vmcnt(0) drain -> buffer0 ready
  int cur = 0;
  for (int ks = 0; ks < 8; ++ks) {
    if (ks < 7) STAGE(cur ^ 1, ks + 1);  // loads fly under this iter's MFMAs
    const char* sb = lds + cur * 28672;
    const int aoff = ((w * 16 + l15) * 32 + l4 * 8) * 2;
    const bf16x8 aXH = *(const bf16x8*)(sb + aoff);
    const bf16x8 aXL = *(const bf16x8*)(sb + 8192 + aoff);
    const int boff = (l15 * 32 + l4 * 8) * 2;
#pragma unroll
    for (int cf = 0; cf < 4; ++cf) {
      const bf16x8 bWF = *(const bf16x8*)(sb + 16384 + cf * 1024 + boff);
      afx[cf] = MFMA(aXH, bWF, afx[cf]);
      const bf16x8 bCH = *(const bf16x8*)(sb + 20480 + cf * 1024 + boff);
      alg[cf] = MFMA(aXH, bCH, alg[cf]);
      alg[cf] = MFMA(aXL, bCH, alg[cf]);
      const bf16x8 bCL = *(const bf16x8*)(sb + 24576 + cf * 1024 + boff);
      alg[cf] = MFMA(aXH, bCL, alg[cf]);
    }
    __syncthreads();  // waits own next-stage loads + all waves' reads done
    cur ^= 1;
  }
#undef STAGE

  // ---- spill fxT[c][n] (b64-packed; staging buffers dead)
#pragma unroll
  for (int cf = 0; cf < 4; ++cf)
    *(uint2*)&fxT[(cf * 16 + l15) * 136 + w * 16 + l4 * 4] = pack4(afx[cf]);

  // ---- softmax over g (rows n = w*16 + l4*4 + r; cols g = cf*16 + l15)
  float tmp = temperature[h];
  tmp = fminf(fmaxf(tmp, 0.1f), 5.0f);
  const float itemp = 1.0f / tmp;
  float wv[4][4];  // [r][gf]
#pragma unroll
  for (int r = 0; r < 4; ++r) {
    float m = fmaxf(fmaxf(alg[0][r], alg[1][r]), fmaxf(alg[2][r], alg[3][r])) * itemp;
    m = fmaxf(m, __shfl_xor(m, 1));
    m = fmaxf(m, __shfl_xor(m, 2));
    m = fmaxf(m, __shfl_xor(m, 4));
    m = fmaxf(m, __shfl_xor(m, 8));
    float s = 0.f;
#pragma unroll
    for (int gf = 0; gf < 4; ++gf) {
      wv[r][gf] = __expf(alg[gf][r] * itemp - m);
      s += wv[r][gf];
    }
    s += __shfl_xor(s, 1);
    s += __shfl_xor(s, 2);
    s += __shfl_xor(s, 4);
    s += __shfl_xor(s, 8);
    const float inv = 1.0f / s;
#pragma unroll
    for (int gf = 0; gf < 4; ++gf) wv[r][gf] *= inv;
  }

  // norm partials
#pragma unroll
  for (int gf = 0; gf < 4; ++gf) {
    float pn = wv[0][gf] + wv[1][gf] + wv[2][gf] + wv[3][gf];
    pn += __shfl_xor(pn, 16);
    pn += __shfl_xor(pn, 32);
    if (l4 == 0) atomicAdd(&nrm[bh * 64 + gf * 16 + l15], pn);
  }

  // wT[g][n] (b64)
#pragma unroll
  for (int gf = 0; gf < 4; ++gf) {
    f32x4 v;
    v[0] = wv[0][gf]; v[1] = wv[1][gf]; v[2] = wv[2][gf]; v[3] = wv[3][gf];
    *(uint2*)&wT[(gf * 16 + l15) * 136 + w * 16 + l4 * 4] = pack4(v);
  }
  __syncthreads();

  // ---- w_buf global store (coalesced) via wT re-read
  {
    const int n = t >> 2, q = t & 3;
    unsigned up[8];
#pragma unroll
    for (int j = 0; j < 8; ++j) {
      const unsigned e0 = wT[(q * 16 + 2 * j) * 136 + n];
      const unsigned e1 = wT[(q * 16 + 2 * j + 1) * 136 + n];
      up[j] = e0 | (e1 << 16);
    }
    ushort_t* wg = w_buf + ((size_t)bh * N_ + n0 + n) * 64 + q * 16;
    *(int4*)&wg[0] = *(int4*)&up[0];
    *(int4*)&wg[8] = *(int4*)&up[4];
  }

  // ---- pooling: D[g x c] = wT[g][n] @ fxT[c][n]^T, K=128
  f32x4 ap[2];
  ap[0] = (f32x4)0.f;
  ap[1] = (f32x4)0.f;
  const int gf0 = (w * 2) >> 2, cf0 = (w * 2) & 3;
  const int gf1 = (w * 2 + 1) >> 2, cf1 = (w * 2 + 1) & 3;
#pragma unroll
  for (int ks = 0; ks < 4; ++ks) {
    const bf16x8 aW0 = *(const bf16x8*)&wT[(gf0 * 16 + l15) * 136 + ks * 32 + l4 * 8];
    const bf16x8 bF0 = *(const bf16x8*)&fxT[(cf0 * 16 + l15) * 136 + ks * 32 + l4 * 8];
    ap[0] = MFMA(aW0, bF0, ap[0]);
    const bf16x8 aW1 = *(const bf16x8*)&wT[(gf1 * 16 + l15) * 136 + ks * 32 + l4 * 8];
    const bf16x8 bF1 = *(const bf16x8*)&fxT[(cf1 * 16 + l15) * 136 + ks * 32 + l4 * 8];
    ap[1] = MFMA(aW1, bF1, ap[1]);
  }
#pragma unroll
  for (int u = 0; u < 2; ++u) {
    const int gf = (w * 2 + u) >> 2, cf = (w * 2 + u) & 3;
    const int c = cf * 16 + l15;
#pragma unroll
    for (int r = 0; r < 4; ++r) {
      const int g = gf * 16 + l4 * 4 + r;
      atomicAdd(&tok[((size_t)bh * 64 + g) * 64 + c], ap[u][r]);
    }
  }
}

// ---------------------------------------------------------------- K2
__global__ __launch_bounds__(256) void k2_attn(
    const float* __restrict__ tok, const float* __restrict__ nrm,
    const float* __restrict__ Wq, const float* __restrict__ Wk,
    const float* __restrict__ Wv, ushort_t* __restrict__ outST) {
  __shared__ float st[64 * 65];
  __shared__ float qs[64 * 65];
  __shared__ float ks[64 * 68];
  __shared__ float vs[64 * 68];
  const int t = threadIdx.x;
  const int g = t & 63, qd = t >> 6;
  const int bh = blockIdx.x;

  const float rn = 1.0f / (nrm[bh * 64 + g] + 1e-5f);
  const float* tkr = tok + (size_t)bh * 4096 + g * 64;
#pragma unroll
  for (int dd = 0; dd < 16; ++dd) {
    const int d = qd * 16 + dd;
    st[g * 65 + d] = tkr[d] * rn;
  }
  __syncthreads();

  float qa[16], ka[16], va[16];
#pragma unroll
  for (int dd = 0; dd < 16; ++dd) { qa[dd] = 0.f; ka[dd] = 0.f; va[dd] = 0.f; }
  for (int c = 0; c < 64; ++c) {
    const float s = st[g * 65 + c];
    const float* wqp = Wq + c * 64 + qd * 16;
    const float* wkp = Wk + c * 64 + qd * 16;
    const float* wvp = Wv + c * 64 + qd * 16;
#pragma unroll
    for (int dd = 0; dd < 16; ++dd) {
      qa[dd] += s * wqp[dd];
      ka[dd] += s * wkp[dd];
      va[dd] += s * wvp[dd];
    }
  }
#pragma unroll
  for (int dd = 0; dd < 16; ++dd) {
    const int d = qd * 16 + dd;
    qs[g * 65 + d] = qa[dd];
    ks[g * 68 + d] = ka[dd];
    vs[g * 68 + d] = va[dd];
  }
  __syncthreads();

  float qr[64];
#pragma unroll
  for (int c = 0; c < 64; ++c) qr[c] = qs[g * 65 + c];
  float sc[16];
#pragma unroll
  for (int jj = 0; jj < 16; ++jj) {
    const int j = qd * 16 + jj;
    float a = 0.f;
#pragma unroll
    for (int c4 = 0; c4 < 16; ++c4) {
      const float4 kv = *(float4*)&ks[j * 68 + c4 * 4];
      a += qr[c4 * 4 + 0] * kv.x + qr[c4 * 4 + 1] * kv.y +
           qr[c4 * 4 + 2] * kv.z + qr[c4 * 4 + 3] * kv.w;
    }
    sc[jj] = a * SCALE_;
  }

  float* red = st;
  float m = sc[0];
#pragma unroll
  for (int jj = 1; jj < 16; ++jj) m = fmaxf(m, sc[jj]);
  red[qd * 64 + g] = m;
  __syncthreads();
  m = fmaxf(fmaxf(red[g], red[64 + g]), fmaxf(red[128 + g], red[192 + g]));
  float s = 0.f;
#pragma unroll
  for (int jj = 0; jj < 16; ++jj) {
    sc[jj] = __expf(sc[jj] - m);
    s += sc[jj];
  }
  red[256 + qd * 64 + g] = s;
  __syncthreads();
  s = red[256 + g] + red[256 + 64 + g] + red[256 + 128 + g] + red[256 + 192 + g];
  const float inv = 1.0f / s;
#pragma unroll
  for (int jj = 0; jj < 16; ++jj) qs[g * 65 + qd * 16 + jj] = sc[jj] * inv;
  __syncthreads();

  float pr[64];
#pragma unroll
  for (int c = 0; c < 64; ++c) pr[c] = qs[g * 65 + c];
  ushort_t* os = outST + (size_t)bh * 4096;
#pragma unroll
  for (int dd = 0; dd < 16; ++dd) {
    const int d = qd * 16 + dd;
    float o = 0.f;
#pragma unroll
    for (int j = 0; j < 64; ++j) o += pr[j] * vs[j * 68 + d];
    os[d * 64 + g] = f2bf(o);  // transposed [c][g]
  }
}

// ---------------------------------------------------------------- K3
__global__ __launch_bounds__(512, 1) void k3_out(
    const ushort_t* __restrict__ w_buf, const ushort_t* __restrict__ outST,
    const ushort_t* __restrict__ wot, const float* __restrict__ bout,
    float* __restrict__ out) {
  __shared__ ushort_t a_lds[128 * 72];
  __shared__ ushort_t wot_lds[256 * 72];
  const int t = threadIdx.x;
  const int l = t & 63, w = t >> 6;
  const int l15 = l & 15, l4 = l >> 4;
  const int bid = blockIdx.x;
  const int tile = bid & 127, b = bid >> 7;
  const int n0 = tile * 128;

  f32x4 acc[16];
#pragma unroll
  for (int df = 0; df < 16; ++df)
#pragma unroll
    for (int r = 0; r < 4; ++r) acc[df][r] = bout[df * 16 + l4 * 4 + r];

  for (int h = 0; h < H_; ++h) {
    const int bh = b * H_ + h;
    __syncthreads();
#pragma unroll
    for (int i = 0; i < 4; ++i) {
      const int idx = t + 512 * i;
      const int row = idx >> 3, q = idx & 7;
      *(int4*)&wot_lds[row * 72 + q * 8] =
          *(const int4*)&wot[((size_t)h * 256 + row) * 64 + q * 8];
    }
    // GEMM1: D[c x n] = outST[c][g] @ w[n][g]^T
    f32x4 as_[4];
#pragma unroll
    for (int cf = 0; cf < 4; ++cf) as_[cf] = (f32x4)0.f;
#pragma unroll
    for (int ks = 0; ks < 2; ++ks) {
      const bf16x8 bW = *(const bf16x8*)&w_buf[((size_t)bh * N_ + n0 + w * 16 + l15) * 64 +
                                               ks * 32 + l4 * 8];
#pragma unroll
      for (int cf = 0; cf < 4; ++cf) {
        const bf16x8 aS = *(const bf16x8*)&outST[(size_t)bh * 4096 + (cf * 16 + l15) * 64 +
                                                 ks * 32 + l4 * 8];
        as_[cf] = MFMA(aS, bW, as_[cf]);
      }
    }
#pragma unroll
    for (int cf = 0; cf < 4; ++cf)
      *(uint2*)&a_lds[(w * 16 + l15) * 72 + cf * 16 + l4 * 4] = pack4(as_[cf]);
    __syncthreads();
    // GEMM2: D[d x n] += Wot[d][c] @ A[n][c]^T
#pragma unroll
    for (int ks = 0; ks < 2; ++ks) {
      const bf16x8 bA = *(const bf16x8*)&a_lds[(w * 16 + l15) * 72 + ks * 32 + l4 * 8];
#pragma unroll
      for (int df = 0; df < 16; ++df) {
        const bf16x8 aW = *(const bf16x8*)&wot_lds[(df * 16 + l15) * 72 + ks * 32 + l4 * 8];
        acc[df] = MFMA(aW, bA, acc[df]);
      }
    }
  }

  const int n = n0 + w * 16 + l15;
  float* og = out + ((size_t)b * N_ + n) * DIM_;
#pragma unroll
  for (int df = 0; df < 16; ++df) {
    float4 v;
    v.x = acc[df][0]; v.y = acc[df][1]; v.z = acc[df][2]; v.w = acc[df][3];
    *(float4*)&og[df * 16 + l4 * 4] = v;
  }
}

// ---------------------------------------------------------------- launch
extern "C" void kernel_launch(void* const* d_in, const int* in_sizes, int n_in,
                              void* d_out, int out_size, void* d_ws, size_t ws_size,
                              hipStream_t stream) {
  const float* x = (const float*)d_in[0];
  const float* Wfx = (const float*)d_in[1];
  const float* bfx = (const float*)d_in[2];
  const float* Wx = (const float*)d_in[3];
  const float* bx = (const float*)d_in[4];
  const float* Wsl = (const float*)d_in[5];
  const float* bsl = (const float*)d_in[6];
  const float* Wq = (const float*)d_in[7];
  const float* Wk = (const float*)d_in[8];
  const float* Wv = (const float*)d_in[9];
  const float* Wout = (const float*)d_in[10];
  const float* bout = (const float*)d_in[11];
  const float* temp = (const float*)d_in[12];

  char* ws = (char*)d_ws;
  ushort_t* w_buf = (ushort_t*)ws;                     // 64 MiB
  ushort_t* xh = (ushort_t*)(ws + 67108864);           // 32 MiB
  ushort_t* xl = (ushort_t*)(ws + 100663296);          // 32 MiB
  ushort_t* wfxt = (ushort_t*)(ws + 134217728);        // 256 KiB
  ushort_t* wcth = (ushort_t*)(ws + 134479872);        // 256 KiB
  ushort_t* wctl = (ushort_t*)(ws + 134742016);        // 256 KiB
  ushort_t* wot = (ushort_t*)(ws + 135004160);         // 256 KiB
  ushort_t* outST = (ushort_t*)(ws + 135266304);       // 256 KiB
  float* tok = (float*)(ws + 135528448);               // 512 KiB
  float* nrm = (float*)(ws + 136052736);               // 8 KiB
  float* lbias = (float*)(ws + 136060928);             // 2 KiB

  hipMemsetAsync(tok, 0, 524288 + 8192, stream);

  k0_prep<<<dim3(3072), dim3(256), 0, stream>>>(x, Wfx, Wout, xh, xl, wfxt, wot);
  k0b_comb<<<dim3(8), dim3(256), 0, stream>>>(Wx, Wsl, bx, bsl, wcth, wctl, lbias);
  k1_proj<<<dim3(B_ * H_ * (N_ / 128)), dim3(512), 0, stream>>>(
      xh, xl, wfxt, wcth, wctl, bfx, lbias, temp, w_buf, tok, nrm);
  k2_attn<<<dim3(B_ * H_), dim3(256), 0, stream>>>(tok, nrm, Wq, Wk, Wv, outST);
  k3_out<<<dim3(B_ * (N_ / 128)), dim3(512), 0, stream>>>(w_buf, outST, wot,
                                                          bout, (float*)d_out);
}

// Round 7
// 470.183 us; speedup vs baseline: 2.9334x; 1.0946x over previous
//
#include <hip/hip_runtime.h>
#include <hip/hip_bf16.h>

// PhysicsAttention MFMA bf16 v3 — k1: persistent swizzled B in LDS, barrier-free
// K-loop, A operands direct global->register, 256-row tiles.
// B=4, N=16384, DIM=256, H=8, D=64, G=64, INNER=512.

#define B_ 4
#define N_ 16384
#define DIM_ 256
#define H_ 8
#define D_ 64
#define G_ 64
#define INNER_ 512
#define SCALE_ 0.125f
#define TILE_ 256

typedef __attribute__((ext_vector_type(8))) short bf16x8;
typedef __attribute__((ext_vector_type(4))) float f32x4;
typedef unsigned short ushort_t;

#define MFMA(a, b, c) __builtin_amdgcn_mfma_f32_16x16x32_bf16((a), (b), (c), 0, 0, 0)

__device__ __forceinline__ ushort_t f2bf(float f) {
  unsigned u = __builtin_bit_cast(unsigned, f);
  u += 0x7FFFu + ((u >> 16) & 1u);
  return (ushort_t)(u >> 16);
}
__device__ __forceinline__ float bf2f(ushort_t h) {
  return __builtin_bit_cast(float, ((unsigned)h) << 16);
}
__device__ __forceinline__ uint2 pack4(f32x4 v) {
  uint2 r;
  r.x = (unsigned)f2bf(v[0]) | ((unsigned)f2bf(v[1]) << 16);
  r.y = (unsigned)f2bf(v[2]) | ((unsigned)f2bf(v[3]) << 16);
  return r;
}
__device__ __forceinline__ void gload16(const ushort_t* gsrc, char* ldst) {
  __builtin_amdgcn_global_load_lds(
      (const __attribute__((address_space(1))) unsigned int*)gsrc,
      (__attribute__((address_space(3))) unsigned int*)ldst, 16, 0, 0);
}

// ---------------------------------------------------------------- k0_prep
__global__ __launch_bounds__(256) void k0_prep(
    const float* __restrict__ x, const float* __restrict__ Wfx,
    const float* __restrict__ Wout, ushort_t* __restrict__ xh,
    ushort_t* __restrict__ xl, ushort_t* __restrict__ wfxt,
    ushort_t* __restrict__ wot) {
  const int bid = blockIdx.x;
  const int t = threadIdx.x;
  if (bid < 2048) {
    const float4* x4 = (const float4*)x;
    const int base = bid * 256 + t;
#pragma unroll
    for (int i = 0; i < 8; ++i) {
      const int idx = base + i * 524288;
      const float4 v = x4[idx];
      ushort_t h0 = f2bf(v.x), h1 = f2bf(v.y), h2 = f2bf(v.z), h3 = f2bf(v.w);
      uint2 hp, lp;
      hp.x = (unsigned)h0 | ((unsigned)h1 << 16);
      hp.y = (unsigned)h2 | ((unsigned)h3 << 16);
      lp.x = (unsigned)f2bf(v.x - bf2f(h0)) | ((unsigned)f2bf(v.y - bf2f(h1)) << 16);
      lp.y = (unsigned)f2bf(v.z - bf2f(h2)) | ((unsigned)f2bf(v.w - bf2f(h3)) << 16);
      *(uint2*)&xh[(size_t)idx * 4] = hp;
      *(uint2*)&xl[(size_t)idx * 4] = lp;
    }
  } else if (bid < 2560) {
    // wfxt [h][c=64][k=256] = W_fx[k][h*64+c]
    const int f = (bid - 2048) * 256 + t;
    const int k = f & 255, c = (f >> 8) & 63, h = f >> 14;
    wfxt[f] = f2bf(Wfx[(size_t)k * INNER_ + h * 64 + c]);
  } else {
    // wot [h][d=256][c=64] = W_out[h*64+c][d]
    const int idx = (bid - 2560) * 256 + t;
    const int c = idx & 63, d = (idx >> 6) & 255, h = idx >> 14;
    wot[idx] = f2bf(Wout[(size_t)(h * 64 + c) * DIM_ + d]);
  }
}

// ---------------------------------------------------------------- k0b
__global__ __launch_bounds__(256) void k0b_comb(
    const float* __restrict__ Wx, const float* __restrict__ Wsl,
    const float* __restrict__ bx, const float* __restrict__ bsl,
    ushort_t* __restrict__ wcth, ushort_t* __restrict__ wctl,
    float* __restrict__ lbias) {
  __shared__ float wsl_s[4096];
  __shared__ float wx_s[64 * 65];
  const int h = blockIdx.x;
  const int t = threadIdx.x;
#pragma unroll
  for (int i = 0; i < 16; ++i) wsl_s[i * 256 + t] = Wsl[i * 256 + t];
  __syncthreads();
  if (t < 64) {
    float a = bsl[t];
    for (int dd = 0; dd < 64; ++dd) a += bx[h * 64 + dd] * wsl_s[dd * 64 + t];
    lbias[h * 64 + t] = a;
  }
  const int g = t & 63, ko = t >> 6;
  for (int kc = 0; kc < 4; ++kc) {
    __syncthreads();
#pragma unroll
    for (int i = 0; i < 16; ++i) {
      const int f = i * 256 + t;
      wx_s[(f >> 6) * 65 + (f & 63)] =
          Wx[(size_t)(kc * 64 + (f >> 6)) * INNER_ + h * 64 + (f & 63)];
    }
    __syncthreads();
    for (int kk = ko * 16; kk < ko * 16 + 16; ++kk) {
      float a = 0.f;
#pragma unroll 8
      for (int dd = 0; dd < 64; ++dd) a += wx_s[kk * 65 + dd] * wsl_s[dd * 64 + g];
      const int k = kc * 64 + kk;
      const ushort_t hi = f2bf(a);
      wcth[(size_t)(h * 64 + g) * 256 + k] = hi;
      wctl[(size_t)(h * 64 + g) * 256 + k] = f2bf(a - bf2f(hi));
    }
  }
}

// ---------------------------------------------------------------- K1
// LDS: persistent B: wf[64][256] @0 (32KB), wch @32768, wcl @65536 — each row
// 512B = 32 x 16B chunks, chunk c holds source chunk c^(row&7) (swizzled via
// per-lane global source address; gload16 dest stays linear).
// Post-loop overlay: fxT[64][264] @0, wT[64][264] @33792.
__global__ __launch_bounds__(512, 2) void k1_proj(
    const ushort_t* __restrict__ xh, const ushort_t* __restrict__ xl,
    const ushort_t* __restrict__ wfxt, const ushort_t* __restrict__ wcth,
    const ushort_t* __restrict__ wctl, const float* __restrict__ bfx,
    const float* __restrict__ lbias, const float* __restrict__ temperature,
    ushort_t* __restrict__ w_buf, float* __restrict__ tok,
    float* __restrict__ nrm) {
  __shared__ __align__(16) char lds[98304];
  ushort_t* fxT = (ushort_t*)lds;            // [64][264] post-loop
  ushort_t* wT = (ushort_t*)(lds + 33792);   // [64][264] post-loop

  const int t = threadIdx.x;
  const int l = t & 63, w = t >> 6;
  const int l15 = l & 15, l4 = l >> 4;
  const int bid = blockIdx.x;
  const int tile = bid & 63, h = (bid >> 6) & 7, b = bid >> 9;
  const int n0 = tile * TILE_;
  const int bh = b * H_ + h;

  const ushort_t* xhg = xh + ((size_t)b * N_ + n0) * 256;
  const ushort_t* xlg = xl + ((size_t)b * N_ + n0) * 256;
  const ushort_t* wfg = wfxt + h * 16384;
  const ushort_t* wchg = wcth + h * 16384;
  const ushort_t* wclg = wctl + h * 16384;

  // ---- stage B once: 6144 x 16B chunks, source-side swizzle
#pragma unroll
  for (int it = 0; it < 12; ++it) {
    const int ci = it * 512 + t;
    const int m = ci >> 11;                 // wave-uniform (2048 % 64 == 0)
    const int cm = ci & 2047;
    const int row = cm >> 5, c = cm & 31;
    const int sc = c ^ (row & 7);
    const ushort_t* src = (m == 0) ? wfg : (m == 1) ? wchg : wclg;
    gload16(src + row * 256 + sc * 8, lds + ci * 16);
  }
  __syncthreads();  // vmcnt(0) drain: B resident

  // ---- accumulators (+bias)
  f32x4 afx[2][4], alg[2][4];
#pragma unroll
  for (int cf = 0; cf < 4; ++cf) {
    const float bf_ = bfx[h * 64 + cf * 16 + l15];
    const float lb_ = lbias[h * 64 + cf * 16 + l15];
#pragma unroll
    for (int rf = 0; rf < 2; ++rf) {
      afx[rf][cf][0] = bf_; afx[rf][cf][1] = bf_; afx[rf][cf][2] = bf_; afx[rf][cf][3] = bf_;
      alg[rf][cf][0] = lb_; alg[rf][cf][1] = lb_; alg[rf][cf][2] = lb_; alg[rf][cf][3] = lb_;
    }
  }

  const int arow = (w * 32 + l15) * 256 + l4 * 8;  // halves
  const int key = l15 & 7;

  // ---- barrier-free K-loop: A global->reg, B swizzled LDS
#pragma unroll
  for (int ks = 0; ks < 8; ++ks) {
    const int kh = ks * 32;
    const bf16x8 xh0 = *(const bf16x8*)&xhg[arow + kh];
    const bf16x8 xh1 = *(const bf16x8*)&xhg[arow + 4096 + kh];
    const bf16x8 xl0 = *(const bf16x8*)&xlg[arow + kh];
    const bf16x8 xl1 = *(const bf16x8*)&xlg[arow + 4096 + kh];
#pragma unroll
    for (int cf = 0; cf < 4; ++cf) {
      const int coff = (cf * 16 + l15) * 512 + (((ks * 4 + l4) ^ key) * 16);
      const bf16x8 bF = *(const bf16x8*)(lds + coff);
      const bf16x8 bH = *(const bf16x8*)(lds + 32768 + coff);
      const bf16x8 bL = *(const bf16x8*)(lds + 65536 + coff);
      afx[0][cf] = MFMA(xh0, bF, afx[0][cf]);
      afx[1][cf] = MFMA(xh1, bF, afx[1][cf]);
      alg[0][cf] = MFMA(xh0, bH, alg[0][cf]);
      alg[0][cf] = MFMA(xl0, bH, alg[0][cf]);
      alg[0][cf] = MFMA(xh0, bL, alg[0][cf]);
      alg[1][cf] = MFMA(xh1, bH, alg[1][cf]);
      alg[1][cf] = MFMA(xl1, bH, alg[1][cf]);
      alg[1][cf] = MFMA(xh1, bL, alg[1][cf]);
    }
  }
  __syncthreads();  // all B reads done before overlay writes

  // ---- spill fxT[c][n] (b64)
#pragma unroll
  for (int rf = 0; rf < 2; ++rf)
#pragma unroll
    for (int cf = 0; cf < 4; ++cf)
      *(uint2*)&fxT[(cf * 16 + l15) * 264 + w * 32 + rf * 16 + l4 * 4] =
          pack4(afx[rf][cf]);

  // ---- softmax over g (rows n = w*32 + rf*16 + l4*4 + r; cols g = gf*16 + l15)
  float tmp = temperature[h];
  tmp = fminf(fmaxf(tmp, 0.1f), 5.0f);
  const float itemp = 1.0f / tmp;
  float wv[2][4][4];  // [rf][r][gf]
#pragma unroll
  for (int rf = 0; rf < 2; ++rf)
#pragma unroll
    for (int r = 0; r < 4; ++r) {
      float m = fmaxf(fmaxf(alg[rf][0][r], alg[rf][1][r]),
                      fmaxf(alg[rf][2][r], alg[rf][3][r])) * itemp;
      m = fmaxf(m, __shfl_xor(m, 1));
      m = fmaxf(m, __shfl_xor(m, 2));
      m = fmaxf(m, __shfl_xor(m, 4));
      m = fmaxf(m, __shfl_xor(m, 8));
      float s = 0.f;
#pragma unroll
      for (int gf = 0; gf < 4; ++gf) {
        wv[rf][r][gf] = __expf(alg[rf][gf][r] * itemp - m);
        s += wv[rf][r][gf];
      }
      s += __shfl_xor(s, 1);
      s += __shfl_xor(s, 2);
      s += __shfl_xor(s, 4);
      s += __shfl_xor(s, 8);
      const float inv = 1.0f / s;
#pragma unroll
      for (int gf = 0; gf < 4; ++gf) wv[rf][r][gf] *= inv;
    }

  // ---- norm partials
#pragma unroll
  for (int gf = 0; gf < 4; ++gf) {
    float pn = 0.f;
#pragma unroll
    for (int rf = 0; rf < 2; ++rf)
#pragma unroll
      for (int r = 0; r < 4; ++r) pn += wv[rf][r][gf];
    pn += __shfl_xor(pn, 16);
    pn += __shfl_xor(pn, 32);
    if (l4 == 0) atomicAdd(&nrm[bh * 64 + gf * 16 + l15], pn);
  }

  // ---- wT[g][n] (b64)
#pragma unroll
  for (int rf = 0; rf < 2; ++rf)
#pragma unroll
    for (int gf = 0; gf < 4; ++gf) {
      f32x4 v;
      v[0] = wv[rf][0][gf]; v[1] = wv[rf][1][gf];
      v[2] = wv[rf][2][gf]; v[3] = wv[rf][3][gf];
      *(uint2*)&wT[(gf * 16 + l15) * 264 + w * 32 + rf * 16 + l4 * 4] = pack4(v);
    }
  __syncthreads();

  // ---- w_buf global store (coalesced) via wT re-read
  {
    const int n = t >> 1, q = t & 1;
    unsigned up[16];
#pragma unroll
    for (int j = 0; j < 16; ++j) {
      const unsigned e0 = wT[(q * 32 + 2 * j) * 264 + n];
      const unsigned e1 = wT[(q * 32 + 2 * j + 1) * 264 + n];
      up[j] = e0 | (e1 << 16);
    }
    ushort_t* wg = w_buf + ((size_t)bh * N_ + n0 + n) * 64 + q * 32;
    *(int4*)&wg[0] = *(int4*)&up[0];
    *(int4*)&wg[8] = *(int4*)&up[4];
    *(int4*)&wg[16] = *(int4*)&up[8];
    *(int4*)&wg[24] = *(int4*)&up[12];
  }

  // ---- pooling: D[g x c] = wT[g][n] @ fxT[c][n]^T, K=256
  f32x4 ap[2];
  ap[0] = (f32x4)0.f;
  ap[1] = (f32x4)0.f;
  const int gf0 = (w * 2) >> 2, cf0 = (w * 2) & 3;
  const int gf1 = (w * 2 + 1) >> 2, cf1 = (w * 2 + 1) & 3;
#pragma unroll
  for (int ks = 0; ks < 8; ++ks) {
    const bf16x8 aW0 = *(const bf16x8*)&wT[(gf0 * 16 + l15) * 264 + ks * 32 + l4 * 8];
    const bf16x8 bF0 = *(const bf16x8*)&fxT[(cf0 * 16 + l15) * 264 + ks * 32 + l4 * 8];
    ap[0] = MFMA(aW0, bF0, ap[0]);
    const bf16x8 aW1 = *(const bf16x8*)&wT[(gf1 * 16 + l15) * 264 + ks * 32 + l4 * 8];
    const bf16x8 bF1 = *(const bf16x8*)&fxT[(cf1 * 16 + l15) * 264 + ks * 32 + l4 * 8];
    ap[1] = MFMA(aW1, bF1, ap[1]);
  }
#pragma unroll
  for (int u = 0; u < 2; ++u) {
    const int gf = (w * 2 + u) >> 2, cf = (w * 2 + u) & 3;
    const int c = cf * 16 + l15;
#pragma unroll
    for (int r = 0; r < 4; ++r) {
      const int g = gf * 16 + l4 * 4 + r;
      atomicAdd(&tok[((size_t)bh * 64 + g) * 64 + c], ap[u][r]);
    }
  }
}

// ---------------------------------------------------------------- K2
__global__ __launch_bounds__(256) void k2_attn(
    const float* __restrict__ tok, const float* __restrict__ nrm,
    const float* __restrict__ Wq, const float* __restrict__ Wk,
    const float* __restrict__ Wv, ushort_t* __restrict__ outST) {
  __shared__ float st[64 * 65];
  __shared__ float qs[64 * 65];
  __shared__ float ks[64 * 68];
  __shared__ float vs[64 * 68];
  const int t = threadIdx.x;
  const int g = t & 63, qd = t >> 6;
  const int bh = blockIdx.x;

  const float rn = 1.0f / (nrm[bh * 64 + g] + 1e-5f);
  const float* tkr = tok + (size_t)bh * 4096 + g * 64;
#pragma unroll
  for (int dd = 0; dd < 16; ++dd) {
    const int d = qd * 16 + dd;
    st[g * 65 + d] = tkr[d] * rn;
  }
  __syncthreads();

  float qa[16], ka[16], va[16];
#pragma unroll
  for (int dd = 0; dd < 16; ++dd) { qa[dd] = 0.f; ka[dd] = 0.f; va[dd] = 0.f; }
  for (int c = 0; c < 64; ++c) {
    const float s = st[g * 65 + c];
    const float* wqp = Wq + c * 64 + qd * 16;
    const float* wkp = Wk + c * 64 + qd * 16;
    const float* wvp = Wv + c * 64 + qd * 16;
#pragma unroll
    for (int dd = 0; dd < 16; ++dd) {
      qa[dd] += s * wqp[dd];
      ka[dd] += s * wkp[dd];
      va[dd] += s * wvp[dd];
    }
  }
#pragma unroll
  for (int dd = 0; dd < 16; ++dd) {
    const int d = qd * 16 + dd;
    qs[g * 65 + d] = qa[dd];
    ks[g * 68 + d] = ka[dd];
    vs[g * 68 + d] = va[dd];
  }
  __syncthreads();

  float qr[64];
#pragma unroll
  for (int c = 0; c < 64; ++c) qr[c] = qs[g * 65 + c];
  float sc[16];
#pragma unroll
  for (int jj = 0; jj < 16; ++jj) {
    const int j = qd * 16 + jj;
    float a = 0.f;
#pragma unroll
    for (int c4 = 0; c4 < 16; ++c4) {
      const float4 kv = *(float4*)&ks[j * 68 + c4 * 4];
      a += qr[c4 * 4 + 0] * kv.x + qr[c4 * 4 + 1] * kv.y +
           qr[c4 * 4 + 2] * kv.z + qr[c4 * 4 + 3] * kv.w;
    }
    sc[jj] = a * SCALE_;
  }

  float* red = st;
  float m = sc[0];
#pragma unroll
  for (int jj = 1; jj < 16; ++jj) m = fmaxf(m, sc[jj]);
  red[qd * 64 + g] = m;
  __syncthreads();
  m = fmaxf(fmaxf(red[g], red[64 + g]), fmaxf(red[128 + g], red[192 + g]));
  float s = 0.f;
#pragma unroll
  for (int jj = 0; jj < 16; ++jj) {
    sc[jj] = __expf(sc[jj] - m);
    s += sc[jj];
  }
  red[256 + qd * 64 + g] = s;
  __syncthreads();
  s = red[256 + g] + red[256 + 64 + g] + red[256 + 128 + g] + red[256 + 192 + g];
  const float inv = 1.0f / s;
#pragma unroll
  for (int jj = 0; jj < 16; ++jj) qs[g * 65 + qd * 16 + jj] = sc[jj] * inv;
  __syncthreads();

  float pr[64];
#pragma unroll
  for (int c = 0; c < 64; ++c) pr[c] = qs[g * 65 + c];
  ushort_t* os = outST + (size_t)bh * 4096;
#pragma unroll
  for (int dd = 0; dd < 16; ++dd) {
    const int d = qd * 16 + dd;
    float o = 0.f;
#pragma unroll
    for (int j = 0; j < 64; ++j) o += pr[j] * vs[j * 68 + d];
    os[d * 64 + g] = f2bf(o);  // transposed [c][g]
  }
}

// ---------------------------------------------------------------- K3
__global__ __launch_bounds__(512, 1) void k3_out(
    const ushort_t* __restrict__ w_buf, const ushort_t* __restrict__ outST,
    const ushort_t* __restrict__ wot, const float* __restrict__ bout,
    float* __restrict__ out) {
  __shared__ ushort_t a_lds[128 * 72];
  __shared__ ushort_t wot_lds[256 * 72];
  const int t = threadIdx.x;
  const int l = t & 63, w = t >> 6;
  const int l15 = l & 15, l4 = l >> 4;
  const int bid = blockIdx.x;
  const int tile = bid & 127, b = bid >> 7;
  const int n0 = tile * 128;

  f32x4 acc[16];
#pragma unroll
  for (int df = 0; df < 16; ++df)
#pragma unroll
    for (int r = 0; r < 4; ++r) acc[df][r] = bout[df * 16 + l4 * 4 + r];

  for (int h = 0; h < H_; ++h) {
    const int bh = b * H_ + h;
    __syncthreads();
#pragma unroll
    for (int i = 0; i < 4; ++i) {
      const int idx = t + 512 * i;
      const int row = idx >> 3, q = idx & 7;
      *(int4*)&wot_lds[row * 72 + q * 8] =
          *(const int4*)&wot[((size_t)h * 256 + row) * 64 + q * 8];
    }
    // GEMM1: D[c x n] = outST[c][g] @ w[n][g]^T
    f32x4 as_[4];
#pragma unroll
    for (int cf = 0; cf < 4; ++cf) as_[cf] = (f32x4)0.f;
#pragma unroll
    for (int ks = 0; ks < 2; ++ks) {
      const bf16x8 bW = *(const bf16x8*)&w_buf[((size_t)bh * N_ + n0 + w * 16 + l15) * 64 +
                                               ks * 32 + l4 * 8];
#pragma unroll
      for (int cf = 0; cf < 4; ++cf) {
        const bf16x8 aS = *(const bf16x8*)&outST[(size_t)bh * 4096 + (cf * 16 + l15) * 64 +
                                                 ks * 32 + l4 * 8];
        as_[cf] = MFMA(aS, bW, as_[cf]);
      }
    }
#pragma unroll
    for (int cf = 0; cf < 4; ++cf)
      *(uint2*)&a_lds[(w * 16 + l15) * 72 + cf * 16 + l4 * 4] = pack4(as_[cf]);
    __syncthreads();
    // GEMM2: D[d x n] += Wot[d][c] @ A[n][c]^T
#pragma unroll
    for (int ks = 0; ks < 2; ++ks) {
      const bf16x8 bA = *(const bf16x8*)&a_lds[(w * 16 + l15) * 72 + ks * 32 + l4 * 8];
#pragma unroll
      for (int df = 0; df < 16; ++df) {
        const bf16x8 aW = *(const bf16x8*)&wot_lds[(df * 16 + l15) * 72 + ks * 32 + l4 * 8];
        acc[df] = MFMA(aW, bA, acc[df]);
      }
    }
  }

  const int n = n0 + w * 16 + l15;
  float* og = out + ((size_t)b * N_ + n) * DIM_;
#pragma unroll
  for (int df = 0; df < 16; ++df) {
    float4 v;
    v.x = acc[df][0]; v.y = acc[df][1]; v.z = acc[df][2]; v.w = acc[df][3];
    *(float4*)&og[df * 16 + l4 * 4] = v;
  }
}

// ---------------------------------------------------------------- launch
extern "C" void kernel_launch(void* const* d_in, const int* in_sizes, int n_in,
                              void* d_out, int out_size, void* d_ws, size_t ws_size,
                              hipStream_t stream) {
  const float* x = (const float*)d_in[0];
  const float* Wfx = (const float*)d_in[1];
  const float* bfx = (const float*)d_in[2];
  const float* Wx = (const float*)d_in[3];
  const float* bx = (const float*)d_in[4];
  const float* Wsl = (const float*)d_in[5];
  const float* bsl = (const float*)d_in[6];
  const float* Wq = (const float*)d_in[7];
  const float* Wk = (const float*)d_in[8];
  const float* Wv = (const float*)d_in[9];
  const float* Wout = (const float*)d_in[10];
  const float* bout = (const float*)d_in[11];
  const float* temp = (const float*)d_in[12];

  char* ws = (char*)d_ws;
  ushort_t* w_buf = (ushort_t*)ws;                     // 64 MiB
  ushort_t* xh = (ushort_t*)(ws + 67108864);           // 32 MiB
  ushort_t* xl = (ushort_t*)(ws + 100663296);          // 32 MiB
  ushort_t* wfxt = (ushort_t*)(ws + 134217728);        // 256 KiB
  ushort_t* wcth = (ushort_t*)(ws + 134479872);        // 256 KiB
  ushort_t* wctl = (ushort_t*)(ws + 134742016);        // 256 KiB
  ushort_t* wot = (ushort_t*)(ws + 135004160);         // 256 KiB
  ushort_t* outST = (ushort_t*)(ws + 135266304);       // 256 KiB
  float* tok = (float*)(ws + 135528448);               // 512 KiB
  float* nrm = (float*)(ws + 136052736);               // 8 KiB
  float* lbias = (float*)(ws + 136060928);             // 2 KiB

  hipMemsetAsync(tok, 0, 524288 + 8192, stream);

  k0_prep<<<dim3(3072), dim3(256), 0, stream>>>(x, Wfx, Wout, xh, xl, wfxt, wot);
  k0b_comb<<<dim3(8), dim3(256), 0, stream>>>(Wx, Wsl, bx, bsl, wcth, wctl, lbias);
  k1_proj<<<dim3(B_ * H_ * (N_ / TILE_)), dim3(512), 0, stream>>>(
      xh, xl, wfxt, wcth, wctl, bfx, lbias, temp, w_buf, tok, nrm);
  k2_attn<<<dim3(B_ * H_), dim3(256), 0, stream>>>(tok, nrm, Wq, Wk, Wv, outST);
  k3_out<<<dim3(B_ * (N_ / 128)), dim3(512), 0, stream>>>(w_buf, outST, wot,
                                                          bout, (float*)d_out);
}